// Round 6
// baseline (34.003 us; speedup 1.0000x reference)
//
#include <hip/hip_runtime.h>

#define FDIM 32
#define LOG2E 1.44269504088896340f

typedef _Float16 half8 __attribute__((ext_vector_type(8)));
typedef float    f32x4 __attribute__((ext_vector_type(4)));
typedef float    f32x2 __attribute__((ext_vector_type(2)));

// base-2 sigmoid: expects z' = z*log2e already scaled; sigma = 1/(1+2^-z')
__device__ __forceinline__ float fsig2(float z2) {
    return __builtin_amdgcn_rcpf(1.0f + __builtin_amdgcn_exp2f(-z2));
}
// true sigmoid (prep only)
__device__ __forceinline__ float fsig(float z) {
    return __builtin_amdgcn_rcpf(1.0f + __builtin_amdgcn_exp2f(-z * LOG2E));
}

// Row-permutation: MFMA A-row rho = 16m + 4h + r  ->  tree slot (slot = node+1,
// heap: root=1, children of q are 2q/2q+1; level d = slots 2^d..2^(d+1)-1).
// Lane (s,h)'s 64 accumulator values are exactly the nodes its walk needs:
//   m=0          -> path slots 1+4h+r   (h==3,r==3 -> dummy slot 0)
//   m=1          -> L4: 16+4h+r
//   m=2..3       -> L5: 32+8h+2*(2(m-2)+(r>>1)) + (r&1)
//   m=4..7       -> L6: 64+16h+4(m-4)+r
//   m=8..15      -> L7: 128+32h+8*((m-8)>>1) + 4*((m-8)&1) + r
__device__ __forceinline__ int row_to_slot(int rho) {
    int m = rho >> 4, h = (rho >> 2) & 3, r = rho & 3;
    if (m == 0)      return (h == 3 && r == 3) ? 0 : 1 + 4 * h + r;
    if (m == 1)      return 16 + 4 * h + r;
    if (m <= 3)      return 32 + 8 * h + 2 * (2 * (m - 2) + (r >> 1)) + (r & 1);
    if (m <= 7)      return 64 + 16 * h + 4 * (m - 4) + r;
    return 128 + 32 * h + 8 * ((m - 8) >> 1) + 4 * ((m - 8) & 1) + r;
}

// Prep (4 blocks x 256 thr; 4 threads per row, 8 k's each):
// Wh[rho][32] = relu(fi)*log2e in f16, negc[rho] = -c*log2e,
// Dtab[y] = {cls[2y]-cls[2y+1], cls[2y+1]}.
__global__ void dtree_prep(const float* __restrict__ fi, const float* __restrict__ fs,
                           const float* __restrict__ cls,
                           _Float16* __restrict__ Wh, float* __restrict__ negc,
                           float* __restrict__ Dtab) {
    int t = blockIdx.x * 256 + threadIdx.x;   // 0..1023
    if (t < 128) {
        float c0 = cls[2 * t], c1 = cls[2 * t + 1];
        Dtab[2 * t]     = c0 - c1;
        Dtab[2 * t + 1] = c1;
    }
    int rho = t >> 2, q = t & 3;              // row, k-quad (k = 8q..8q+7)
    int slot = row_to_slot(rho);
    half8 wv;
    float s = 0.0f;
    if (slot == 0) {
#pragma unroll
        for (int k0 = 0; k0 < 8; ++k0) wv[k0] = (_Float16)0.0f;
    } else {
        int node = slot - 1;
#pragma unroll
        for (int k0 = 0; k0 < 8; ++k0) {
            int k = 8 * q + k0;
            float w = fi[(node << 5) + k];
            w = w > 0.0f ? w : 0.0f;
            wv[k0] = (_Float16)(w * LOG2E);
            s = fmaf(w, fsig(fs[(node << 5) + k]), s);
        }
    }
    *(half8*)(Wh + (rho << 5) + 8 * q) = wv;
    // reduce s across the 4 q-threads (same wave, consecutive lanes)
    s += __shfl_xor(s, 1, 64);
    s += __shfl_xor(s, 2, 64);
    if (q == 0) negc[rho] = -s * LOG2E;
}

// Fused: 4 independent waves/block, 16 samples/wave. 16 MFMAs with permuted W
// put each lane's needed subtree g's straight into its accumulators; sigmoid
// in-register (f32); only 15 path values/sample bounce through LDS.
__global__ __launch_bounds__(256, 4) void dtree_fused(
    const float* __restrict__ x, const _Float16* __restrict__ Wh,
    const float* __restrict__ negc, const float* __restrict__ Dtab,
    float* __restrict__ out)
{
    __shared__ __align__(16) float sNegc[256];        // broadcast reads
    __shared__ __align__(16) float sDtab[4 * 72];     // 72-float h-stride: banks 0/8/16/24
    __shared__ __align__(16) float pbuf[4][16][20];   // path exchange, wave-private

    const int tid = threadIdx.x;
    const int w = tid >> 6;          // wave in block (0..3)
    const int l = tid & 63;
    const int s = l & 15;            // sample col
    const int h = l >> 4;            // 16-lane group
    const int n = blockIdx.x * 64 + w * 16 + s;

    sNegc[tid] = negc[tid];
    sDtab[72 * (tid >> 6) + (tid & 63)] = Dtab[tid];  // rows of 64 -> stride 72
    __syncthreads();

    // B fragment: x[n][8h..8h+7] as f16
    const float* xrow = x + (size_t)n * FDIM + 8 * h;
    f32x4 xv0 = *(const f32x4*)(xrow);
    f32x4 xv1 = *(const f32x4*)(xrow + 4);
    half8 bfrag;
    bfrag[0] = (_Float16)xv0[0]; bfrag[1] = (_Float16)xv0[1];
    bfrag[2] = (_Float16)xv0[2]; bfrag[3] = (_Float16)xv0[3];
    bfrag[4] = (_Float16)xv1[0]; bfrag[5] = (_Float16)xv1[1];
    bfrag[6] = (_Float16)xv1[2]; bfrag[7] = (_Float16)xv1[3];

    // Phase 1: 16 MFMAs; lane (s,h) gets rows 16m+4h+r (slots per row_to_slot)
    // of g*log2e for its own sample. Sigmoid in-register, f32 throughout.
    float gm[16][4];   // all indices compile-time after full unroll
#pragma unroll
    for (int m = 0; m < 16; ++m) {
        half8 afrag = *(const half8*)(Wh + ((16 * m + s) << 5) + 8 * h);
        f32x4 cin = *(const f32x4*)(sNegc + 16 * m + 4 * h);   // LDS broadcast
        f32x4 acc = __builtin_amdgcn_mfma_f32_16x16x32_f16(afrag, bfrag, cin, 0, 0, 0);
        gm[m][0] = fsig2(acc[0]);
        gm[m][1] = fsig2(acc[1]);
        gm[m][2] = fsig2(acc[2]);
        gm[m][3] = fsig2(acc[3]);
        if (m == 0) {   // path slots 1+4h+r -> pbuf[w][s][4h+r]
            f32x4 pv;
            pv[0] = gm[0][0]; pv[1] = gm[0][1]; pv[2] = gm[0][2]; pv[3] = gm[0][3];
            *(f32x4*)(&pbuf[w][s][4 * h]) = pv;
        }
    }

    // Wave-private cross-lane exchange: wave-local wait + scheduler fence.
    asm volatile("s_waitcnt lgkmcnt(0)" ::: "memory");
    __builtin_amdgcn_sched_barrier(0);

    const float* pb = &pbuf[w][s][0];
    float g1   = pb[0];                 // slot 1 (root)
    float gP2  = pb[1 + (h >> 1)];      // slot 2+(h>>1)  (level 1)
    float gP3  = pb[3 + h];             // slot 4+h       (level 2)
    float gP4a = pb[7 + 2 * h];         // slot 8+2h      (level 3)
    float gP4b = pb[8 + 2 * h];         // slot 9+2h

    float f0 = (h & 2) ? 1.0f - g1  : g1;    // leaf bit0 = h>>1
    float f1 = (h & 1) ? 1.0f - gP2 : gP2;   // leaf bit1 = h&1
    float f01 = f0 * f1;

    const float* dtb = sDtab + 72 * h;       // padded: conflict-free across h
    float facc = 0.0f;

#pragma unroll
    for (int j = 0; j < 4; ++j) {            // subtree i = 4h + j
        float f2  = (j & 2) ? 1.0f - gP3 : gP3;       // bit2 = (j>>1)&1
        float gP4 = (j & 2) ? gP4b : gP4a;            // slot 8+2h+(j>>1)
        float f3  = (j & 1) ? 1.0f - gP4 : gP4;       // bit3 = j&1
        float p4  = f01 * (f2 * f3);
        float gD  = gm[1][j];                          // L4: slot 16+4h+j
#pragma unroll
        for (int b4 = 0; b4 < 2; ++b4) {
            float p5 = b4 ? (p4 - p4 * gD) : (p4 * gD);
            float gE = gm[2 + (j >> 1)][2 * (j & 1) + b4];   // L5: 32+8h+2j+b4
#pragma unroll
            for (int b5 = 0; b5 < 2; ++b5) {
                float p6 = b5 ? (p5 - p5 * gE) : (p5 * gE);
                float gF = gm[4 + j][2 * b4 + b5];           // L6: 64+16h+4j+..
#pragma unroll
                for (int b6 = 0; b6 < 2; ++b6) {
                    float p7 = b6 ? (p6 - p6 * gF) : (p6 * gF);
                    int t = 4 * b4 + 2 * b5 + b6;            // static
                    float gG = gm[8 + 2 * j + (t >> 2)][t & 3]; // L7: 128+32h+8j+t
                    f32x2 Dp = *(const f32x2*)(dtb + 16 * j + 2 * t); // {c0-c1,c1}
                    facc = fmaf(p7, fmaf(gG, Dp[0], Dp[1]), facc);
                }
            }
        }
    }

    // combine the 4 h-lanes of each sample
    facc += __shfl_xor(facc, 16, 64);
    facc += __shfl_xor(facc, 32, 64);
    if (h == 0) out[n] = facc;
}

extern "C" void kernel_launch(void* const* d_in, const int* in_sizes, int n_in,
                              void* d_out, int out_size, void* d_ws, size_t ws_size,
                              hipStream_t stream) {
    const float* x   = (const float*)d_in[0];
    const float* fi  = (const float*)d_in[1];
    const float* fs  = (const float*)d_in[2];
    const float* cls = (const float*)d_in[3];

    _Float16* Wh = (_Float16*)d_ws;                        // 256*32*2 = 16 KB
    float* negc  = (float*)((char*)d_ws + 16384);          // 1 KB
    float* Dtab  = negc + 256;                             // 1 KB

    int nsamp = in_sizes[0] / FDIM;                        // 262144
    float* out = (float*)d_out;

    hipLaunchKernelGGL(dtree_prep, dim3(4), dim3(256), 0, stream, fi, fs, cls, Wh, negc, Dtab);
    hipLaunchKernelGGL(dtree_fused, dim3(nsamp / 64), dim3(256), 0, stream,
                       x, Wh, negc, Dtab, out);
}

// Round 7
// 32.178 us; speedup vs baseline: 1.0567x; 1.0567x over previous
//
#include <hip/hip_runtime.h>

#define FDIM 32
#define LOG2E 1.44269504088896340f

typedef _Float16 half8 __attribute__((ext_vector_type(8)));
typedef float    f32x4 __attribute__((ext_vector_type(4)));
typedef float    f32x2 __attribute__((ext_vector_type(2)));

// base-2 sigmoid: expects z' = z*log2e already scaled; sigma = 1/(1+2^-z')
__device__ __forceinline__ float fsig2(float z2) {
    return __builtin_amdgcn_rcpf(1.0f + __builtin_amdgcn_exp2f(-z2));
}
// true sigmoid (prep only)
__device__ __forceinline__ float fsig(float z) {
    return __builtin_amdgcn_rcpf(1.0f + __builtin_amdgcn_exp2f(-z * LOG2E));
}

// Row-permutation: MFMA A-row rho = 16m + 4h + r  ->  tree slot (slot = node+1,
// heap: root=1, children of q are 2q/2q+1; level d = slots 2^d..2^(d+1)-1).
// Lane (s,h)'s 64 accumulator values are exactly the nodes its walk needs:
//   m=0          -> path slots 1+4h+r   (h==3,r==3 -> dummy slot 0)
//   m=1          -> L4: 16+4h+r
//   m=2..3       -> L5: 32+8h+4(m-2)+r
//   m=4..7       -> L6: 64+16h+4(m-4)+r
//   m=8..15      -> L7: 128+32h+8*((m-8)>>1) + 4*((m-8)&1) + r
__device__ __forceinline__ int row_to_slot(int rho) {
    int m = rho >> 4, h = (rho >> 2) & 3, r = rho & 3;
    if (m == 0)      return (h == 3 && r == 3) ? 0 : 1 + 4 * h + r;
    if (m == 1)      return 16 + 4 * h + r;
    if (m <= 3)      return 32 + 8 * h + 2 * (2 * (m - 2) + (r >> 1)) + (r & 1);
    if (m <= 7)      return 64 + 16 * h + 4 * (m - 4) + r;
    return 128 + 32 * h + 8 * ((m - 8) >> 1) + 4 * ((m - 8) & 1) + r;
}

// Prep (4 blocks x 256 thr; 4 threads per row, 8 k's each):
// Wh[rho][32] = relu(fi)*log2e in f16, negc[rho] = -c*log2e,
// Dtab[y] = {cls[2y]-cls[2y+1], cls[2y+1]}.
__global__ void dtree_prep(const float* __restrict__ fi, const float* __restrict__ fs,
                           const float* __restrict__ cls,
                           _Float16* __restrict__ Wh, float* __restrict__ negc,
                           float* __restrict__ Dtab) {
    int t = blockIdx.x * 256 + threadIdx.x;   // 0..1023
    if (t < 128) {
        float c0 = cls[2 * t], c1 = cls[2 * t + 1];
        Dtab[2 * t]     = c0 - c1;
        Dtab[2 * t + 1] = c1;
    }
    int rho = t >> 2, q = t & 3;              // row, k-quad (k = 8q..8q+7)
    int slot = row_to_slot(rho);
    half8 wv;
    float s = 0.0f;
    if (slot == 0) {
#pragma unroll
        for (int k0 = 0; k0 < 8; ++k0) wv[k0] = (_Float16)0.0f;
    } else {
        int node = slot - 1;
#pragma unroll
        for (int k0 = 0; k0 < 8; ++k0) {
            int k = 8 * q + k0;
            float w = fi[(node << 5) + k];
            w = w > 0.0f ? w : 0.0f;
            wv[k0] = (_Float16)(w * LOG2E);
            s = fmaf(w, fsig(fs[(node << 5) + k]), s);
        }
    }
    *(half8*)(Wh + (rho << 5) + 8 * q) = wv;
    s += __shfl_xor(s, 1, 64);
    s += __shfl_xor(s, 2, 64);
    if (q == 0) negc[rho] = -s * LOG2E;
}

// Upward combine of one depth-4 subtree (16 leaves) from register g's.
// v(node) = g*v_left + (1-g)*v_right = fma(g, vl - vr, vr).
__device__ __forceinline__ float subtree_val(const float* dtbj,
        f32x4 g7a, f32x4 g7b, f32x4 g6, float gE0, float gE1, float gD) {
    f32x4 dA = *(const f32x4*)(dtbj + 0);    // leaf pairs t=0,1: {D0,D1,D0,D1}
    f32x4 dB = *(const f32x4*)(dtbj + 4);    // t=2,3
    f32x4 dC = *(const f32x4*)(dtbj + 8);    // t=4,5
    f32x4 dE = *(const f32x4*)(dtbj + 12);   // t=6,7
    float v70 = fmaf(g7a[0], dA[0], dA[1]);
    float v71 = fmaf(g7a[1], dA[2], dA[3]);
    float v72 = fmaf(g7a[2], dB[0], dB[1]);
    float v73 = fmaf(g7a[3], dB[2], dB[3]);
    float v74 = fmaf(g7b[0], dC[0], dC[1]);
    float v75 = fmaf(g7b[1], dC[2], dC[3]);
    float v76 = fmaf(g7b[2], dE[0], dE[1]);
    float v77 = fmaf(g7b[3], dE[2], dE[3]);
    float v60 = fmaf(g6[0], v70 - v71, v71);
    float v61 = fmaf(g6[1], v72 - v73, v73);
    float v62 = fmaf(g6[2], v74 - v75, v75);
    float v63 = fmaf(g6[3], v76 - v77, v77);
    float v50 = fmaf(gE0, v60 - v61, v61);
    float v51 = fmaf(gE1, v62 - v63, v63);
    return fmaf(gD, v50 - v51, v51);
}

// Fused: 4 independent waves/block, 16 samples/wave. MFMAs interleaved with
// per-subtree upward walks so g-state liveness stays ~28 f32 (occupancy 6/SIMD).
__global__ __launch_bounds__(256, 6) void dtree_fused(
    const float* __restrict__ x, const _Float16* __restrict__ Wh,
    const float* __restrict__ negc, const float* __restrict__ Dtab,
    float* __restrict__ out)
{
    __shared__ __align__(16) float sNegc[256];        // broadcast reads
    __shared__ __align__(16) float sDtab[4 * 72];     // 72-float h-stride: banks 0/8/16/24
    __shared__ __align__(16) float pbuf[4][16][20];   // path exchange, wave-private

    const int tid = threadIdx.x;
    const int w = tid >> 6;          // wave in block (0..3)
    const int l = tid & 63;
    const int s = l & 15;            // sample col
    const int h = l >> 4;            // 16-lane group
    const int n = blockIdx.x * 64 + w * 16 + s;

    sNegc[tid] = negc[tid];
    sDtab[72 * (tid >> 6) + (tid & 63)] = Dtab[tid];
    __syncthreads();

    // B fragment: x[n][8h..8h+7] as f16
    const float* xrow = x + (size_t)n * FDIM + 8 * h;
    f32x4 xv0 = *(const f32x4*)(xrow);
    f32x4 xv1 = *(const f32x4*)(xrow + 4);
    half8 bfrag;
    bfrag[0] = (_Float16)xv0[0]; bfrag[1] = (_Float16)xv0[1];
    bfrag[2] = (_Float16)xv0[2]; bfrag[3] = (_Float16)xv0[3];
    bfrag[4] = (_Float16)xv1[0]; bfrag[5] = (_Float16)xv1[1];
    bfrag[6] = (_Float16)xv1[2]; bfrag[7] = (_Float16)xv1[3];

#define GROW(m, dst) do { \
    half8 afrag_ = *(const half8*)(Wh + ((16 * (m) + s) << 5) + 8 * h); \
    f32x4 cin_ = *(const f32x4*)(sNegc + 16 * (m) + 4 * h); \
    f32x4 acc_ = __builtin_amdgcn_mfma_f32_16x16x32_f16(afrag_, bfrag, cin_, 0, 0, 0); \
    dst[0] = fsig2(acc_[0]); dst[1] = fsig2(acc_[1]); \
    dst[2] = fsig2(acc_[2]); dst[3] = fsig2(acc_[3]); \
} while (0)

    // Path row first; overlap its LDS round-trip with rows 1,2.
    f32x4 pv; GROW(0, pv);
    *(f32x4*)(&pbuf[w][s][4 * h]) = pv;

    f32x4 gL4;  GROW(1, gL4);    // L4 g's, all 4 subtrees
    f32x4 gL5a; GROW(2, gL5a);   // L5 g's, subtrees 0,1

    asm volatile("s_waitcnt lgkmcnt(0)" ::: "memory");
    __builtin_amdgcn_sched_barrier(0);

    const float* pb = &pbuf[w][s][0];
    float g1   = pb[0];                 // slot 1 (root)
    float gP2  = pb[1 + (h >> 1)];      // level 1
    float gP3  = pb[3 + h];             // level 2
    float gP4a = pb[7 + 2 * h];         // level 3, slot 8+2h
    float gP4b = pb[8 + 2 * h];         // level 3, slot 9+2h

    float f0 = (h & 2) ? 1.0f - g1  : g1;
    float f1 = (h & 1) ? 1.0f - gP2 : gP2;
    float f01 = f0 * f1;

    const float* dtb = sDtab + 72 * h;
    float facc = 0.0f;

    { // subtree j=0: rows 4, 8, 9
        f32x4 g6, g7a, g7b;
        GROW(4, g6); GROW(8, g7a); GROW(9, g7b);
        float p4 = f01 * (gP3 * gP4a);
        facc = fmaf(p4, subtree_val(dtb + 0, g7a, g7b, g6, gL5a[0], gL5a[1], gL4[0]), facc);
    }
    { // subtree j=1: rows 5, 10, 11
        f32x4 g6, g7a, g7b;
        GROW(5, g6); GROW(10, g7a); GROW(11, g7b);
        float p4 = f01 * (gP3 * (1.0f - gP4a));
        facc = fmaf(p4, subtree_val(dtb + 16, g7a, g7b, g6, gL5a[2], gL5a[3], gL4[1]), facc);
    }
    f32x4 gL5b; GROW(3, gL5b);   // L5 g's, subtrees 2,3
    { // subtree j=2: rows 6, 12, 13
        f32x4 g6, g7a, g7b;
        GROW(6, g6); GROW(12, g7a); GROW(13, g7b);
        float p4 = f01 * ((1.0f - gP3) * gP4b);
        facc = fmaf(p4, subtree_val(dtb + 32, g7a, g7b, g6, gL5b[0], gL5b[1], gL4[2]), facc);
    }
    { // subtree j=3: rows 7, 14, 15
        f32x4 g6, g7a, g7b;
        GROW(7, g6); GROW(14, g7a); GROW(15, g7b);
        float p4 = f01 * ((1.0f - gP3) * (1.0f - gP4b));
        facc = fmaf(p4, subtree_val(dtb + 48, g7a, g7b, g6, gL5b[2], gL5b[3], gL4[3]), facc);
    }
#undef GROW

    // combine the 4 h-lanes of each sample
    facc += __shfl_xor(facc, 16, 64);
    facc += __shfl_xor(facc, 32, 64);
    if (h == 0) out[n] = facc;
}

extern "C" void kernel_launch(void* const* d_in, const int* in_sizes, int n_in,
                              void* d_out, int out_size, void* d_ws, size_t ws_size,
                              hipStream_t stream) {
    const float* x   = (const float*)d_in[0];
    const float* fi  = (const float*)d_in[1];
    const float* fs  = (const float*)d_in[2];
    const float* cls = (const float*)d_in[3];

    _Float16* Wh = (_Float16*)d_ws;                        // 256*32*2 = 16 KB
    float* negc  = (float*)((char*)d_ws + 16384);          // 1 KB
    float* Dtab  = negc + 256;                             // 1 KB

    int nsamp = in_sizes[0] / FDIM;                        // 262144
    float* out = (float*)d_out;

    hipLaunchKernelGGL(dtree_prep, dim3(4), dim3(256), 0, stream, fi, fs, cls, Wh, negc, Dtab);
    hipLaunchKernelGGL(dtree_fused, dim3(nsamp / 64), dim3(256), 0, stream,
                       x, Wh, negc, Dtab, out);
}